// Round 5
// baseline (816.782 us; speedup 1.0000x reference)
//
#include <hip/hip_runtime.h>
#include <stdint.h>

// Problem constants (QwenAttention: B=2, S=2048, H=16, Dh=128, N_STATE=2048)
#define BS   2
#define SS   2048
#define NH   16
#define DH   128
#define HD   2048            // NH*DH == N_STATE
#define KDIM 2048
#define NT   32              // KDIM / 64 K-tiles

typedef _Float16 half_t;
typedef _Float16 half8 __attribute__((ext_vector_type(8)));
typedef _Float16 half4v __attribute__((ext_vector_type(4)));
typedef float   float4_ __attribute__((ext_vector_type(4)));

// ---- async global->LDS, 16B per lane (LDS dest must be wave-uniform base + lane*16)
__device__ __forceinline__ void async16(const void* g, void* l) {
  __builtin_amdgcn_global_load_lds(
      (__attribute__((address_space(1))) void*)(void*)g,
      (__attribute__((address_space(3))) void*)l,
      16, 0, 0);
}

// ---- fused fp32 -> fp16 conversion for x, Wqkv, Wo in ONE dispatch
#define XN4  2097152
#define WQ4  3145728
#define WO4  1048576
__global__ __launch_bounds__(256) void conv_all(const float* __restrict__ x,
                                                const float* __restrict__ Wqkv,
                                                const float* __restrict__ Wo,
                                                half_t* __restrict__ xh,
                                                half_t* __restrict__ wqh,
                                                half_t* __restrict__ woh) {
  int i = blockIdx.x * 256 + threadIdx.x;   // 0 .. 6291455
  const float* src; half_t* dst; int o;
  if (i < XN4)            { src = x;    dst = xh;  o = i; }
  else if (i < XN4 + WQ4) { src = Wqkv; dst = wqh; o = i - XN4; }
  else                    { src = Wo;   dst = woh; o = i - XN4 - WQ4; }
  float4 v = ((const float4*)src)[o];
  half4v hv;
  hv.x = (half_t)v.x; hv.y = (half_t)v.y; hv.z = (half_t)v.z; hv.w = (half_t)v.w;
  ((half4v*)dst)[o] = hv;
}

// ============================================================================
// GEMMs: 128x128 tile, BK=64, 4 waves (2x2). Distance-2 prefetch, double-
// buffered LDS, counted s_waitcnt vmcnt(8) (never drains to 0 in the main
// loop), raw s_barrier, setprio around MFMA. Verified: 880 TF (r3, 43% Mfma).
// LDS rows hold 8 chunks of 16B; chunk j of row r stored at j ^ (r&7) — XOR
// swizzle keeps ds_read_b128 bank-conflict-free (measured 0 conflicts).
// Staging swizzles the SOURCE address (global_load_lds dest must stay linear).
// ============================================================================

__device__ __forceinline__ const half8* lds_frag(const half_t* l, int row, int j) {
  return (const half8*)&l[(row * 8 + (j ^ (row & 7))) * 8];
}

// stage one 128x64 A-tile + 128x64 B-tile: 8 async16 per thread (256 threads)
__device__ __forceinline__ void stage8(const half_t* __restrict__ Ab,
                                       const half_t* __restrict__ Wb,
                                       half_t* dA, half_t* dB, int k0,
                                       int wave, int lane) {
#pragma unroll
  for (int i = 0; i < 4; ++i) {
    int p = (wave * 4 + i) * 64 + lane;       // chunk position 0..1023
    int r = p >> 3, j = (p & 7) ^ ((p >> 3) & 7);
    async16(Ab + (size_t)r * KDIM + k0 + j * 8, &dA[p * 8]);
    async16(Wb + (size_t)r * KDIM + k0 + j * 8, &dB[p * 8]);
  }
}

__device__ __forceinline__ void gemm_core(const half_t* __restrict__ Ab,
                                          const half_t* __restrict__ Wb,
                                          half_t* lA, half_t* lB,
                                          float4_ acc[4][4]) {
  const int tid = threadIdx.x, wave = tid >> 6, lane = tid & 63;
  const int quad = lane >> 4, tl = lane & 15;
  const int wm = wave >> 1, wn = wave & 1;

  stage8(Ab, Wb, lA, lB, 0, wave, lane);
  stage8(Ab, Wb, lA + 8192, lB + 8192, 64, wave, lane);

  for (int t = 0; t < NT; ++t) {
    if (t == NT - 1) asm volatile("s_waitcnt vmcnt(0)" ::: "memory");
    else             asm volatile("s_waitcnt vmcnt(8)" ::: "memory");
    __builtin_amdgcn_s_barrier();           // buf[t&1] fully staged, block-wide

    const half_t* cA = lA + (t & 1) * 8192;
    const half_t* cB = lB + (t & 1) * 8192;
    half8 af[4][2], bf[4][2];
#pragma unroll
    for (int ks = 0; ks < 2; ++ks) {
#pragma unroll
      for (int mi = 0; mi < 4; ++mi)
        af[mi][ks] = *lds_frag(cA, wm * 64 + mi * 16 + tl, ks * 4 + quad);
#pragma unroll
      for (int ni = 0; ni < 4; ++ni)
        bf[ni][ks] = *lds_frag(cB, wn * 64 + ni * 16 + tl, ks * 4 + quad);
    }
    asm volatile("s_waitcnt lgkmcnt(0)" ::: "memory");
    __builtin_amdgcn_sched_barrier(0);
    __builtin_amdgcn_s_barrier();           // all waves done reading buf[t&1]

    if (t + 2 < NT)                         // refill the buffer just freed
      stage8(Ab, Wb, lA + (t & 1) * 8192, lB + (t & 1) * 8192,
             (t + 2) * 64, wave, lane);
    __builtin_amdgcn_sched_barrier(0);      // keep stage issues ahead of MFMA

    __builtin_amdgcn_s_setprio(1);
#pragma unroll
    for (int mi = 0; mi < 4; ++mi)
#pragma unroll
      for (int ni = 0; ni < 4; ++ni)
#pragma unroll
        for (int ks = 0; ks < 2; ++ks)
          acc[mi][ni] = __builtin_amdgcn_mfma_f32_16x16x32_f16(
              af[mi][ks], bf[ni][ks], acc[mi][ni], 0, 0, 0);
    __builtin_amdgcn_s_setprio(0);
  }
}

// ---- GEMM1: qkv = x @ Wqkv^T + b; epilogue splits q/k/v fp16 and also emits
// v in fp32 straight from the accumulator (saves vpost a full fp32 write pass)
__global__ __launch_bounds__(256) void gemm_qkv(const half_t* __restrict__ A,
                                                const half_t* __restrict__ W,
                                                const float* __restrict__ bias,
                                                half_t* __restrict__ qh,
                                                half_t* __restrict__ kh,
                                                half_t* __restrict__ vh,
                                                float* __restrict__ vout) {
  __shared__ __align__(16) half_t lA[2 * 128 * 64];
  __shared__ __align__(16) half_t lB[2 * 128 * 64];
  const int tid = threadIdx.x, wave = tid >> 6, lane = tid & 63;
  const int quad = lane >> 4, tl = lane & 15;
  const int wm = wave >> 1, wn = wave & 1;
  const int bm = blockIdx.y * 128, bn = blockIdx.x * 128;

  float4_ acc[4][4];
#pragma unroll
  for (int mi = 0; mi < 4; ++mi)
#pragma unroll
    for (int ni = 0; ni < 4; ++ni)
#pragma unroll
      for (int r = 0; r < 4; ++r) acc[mi][ni][r] = 0.f;

  gemm_core(A + (size_t)bm * KDIM, W + (size_t)bn * KDIM, lA, lB, acc);

  // epilogue: C/D layout col=lane&15, row=quad*4+reg
#pragma unroll
  for (int mi = 0; mi < 4; ++mi) {
    int rowb = bm + wm * 64 + mi * 16 + quad * 4;
#pragma unroll
    for (int ni = 0; ni < 4; ++ni) {
      int col = bn + wn * 64 + ni * 16 + tl;
      float bv = bias[col];
#pragma unroll
      for (int r = 0; r < 4; ++r) {
        float v = acc[mi][ni][r] + bv;
        size_t off = (size_t)(rowb + r) * HD;
        if (col < 2048)       qh[off + col]        = (half_t)v;
        else if (col < 4096)  kh[off + col - 2048] = (half_t)v;
        else {
          vh[off + col - 4096]   = (half_t)v;
          vout[off + col - 4096] = v;
        }
      }
    }
  }
}

// ---- GEMM2: out = attn @ Wo^T (fp32 out, no bias)
__global__ __launch_bounds__(256) void gemm_out(const half_t* __restrict__ A,
                                                const half_t* __restrict__ W,
                                                float* __restrict__ out) {
  __shared__ __align__(16) half_t lA[2 * 128 * 64];
  __shared__ __align__(16) half_t lB[2 * 128 * 64];
  const int tid = threadIdx.x, wave = tid >> 6, lane = tid & 63;
  const int quad = lane >> 4, tl = lane & 15;
  const int wm = wave >> 1, wn = wave & 1;
  const int bm = blockIdx.y * 128, bn = blockIdx.x * 128;

  float4_ acc[4][4];
#pragma unroll
  for (int mi = 0; mi < 4; ++mi)
#pragma unroll
    for (int ni = 0; ni < 4; ++ni)
#pragma unroll
      for (int r = 0; r < 4; ++r) acc[mi][ni][r] = 0.f;

  gemm_core(A + (size_t)bm * KDIM, W + (size_t)bn * KDIM, lA, lB, acc);

#pragma unroll
  for (int mi = 0; mi < 4; ++mi) {
    int rowb = bm + wm * 64 + mi * 16 + quad * 4;
#pragma unroll
    for (int ni = 0; ni < 4; ++ni) {
      int col = bn + wn * 64 + ni * 16 + tl;
#pragma unroll
      for (int r = 0; r < 4; ++r)
        out[(size_t)(rowb + r) * HD + col] = acc[mi][ni][r];
    }
  }
}

// ---- RoPE on q,k (in-place on fp16 bufs), also emit fp32 k to d_out.
// Vectorized: each thread handles 8 consecutive (d, d+64) pairs — half8/float4
// loads & stores (G13: scalar bf16/f16 access ~2x slower on hipcc).
__global__ __launch_bounds__(256) void rope_post(half_t* __restrict__ qh,
                                                 half_t* __restrict__ kh,
                                                 const float* __restrict__ fr,
                                                 const float* __restrict__ fi,
                                                 float* __restrict__ kout) {
  int n = blockIdx.x * 256 + threadIdx.x;   // B*S*NH*8 = 524288 threads
  int u = n & 7;
  int h = (n >> 3) & 15;
  int s = (n >> 7) & 2047;
  int b = n >> 18;
  size_t row = (size_t)(b * SS + s);
  size_t base = row * HD + h * DH + u * 8;
  const float4_* fr4 = (const float4_*)(fr + row * 64 + u * 8);
  const float4_* fi4 = (const float4_*)(fi + row * 64 + u * 8);
  float4_ frv0 = fr4[0], frv1 = fr4[1];
  float4_ fiv0 = fi4[0], fiv1 = fi4[1];
  half8 qlo = *(const half8*)(qh + base), qhi = *(const half8*)(qh + base + 64);
  half8 klo = *(const half8*)(kh + base), khi = *(const half8*)(kh + base + 64);
  half8 qlo_o, qhi_o, klo_o, khi_o;
  float4_ kr0, kr1, ki0, ki1;
#pragma unroll
  for (int j = 0; j < 8; ++j) {
    float cr = (j < 4) ? frv0[j & 3] : frv1[j & 3];
    float ci = (j < 4) ? fiv0[j & 3] : fiv1[j & 3];
    float xr = (float)qlo[j], xi = (float)qhi[j];
    qlo_o[j] = (half_t)(xr * cr - xi * ci);
    qhi_o[j] = (half_t)(xr * ci + xi * cr);
    xr = (float)klo[j]; xi = (float)khi[j];
    float kr = xr * cr - xi * ci, ki = xr * ci + xi * cr;
    klo_o[j] = (half_t)kr; khi_o[j] = (half_t)ki;
    if (j < 4) { kr0[j & 3] = kr; ki0[j & 3] = ki; }
    else       { kr1[j & 3] = kr; ki1[j & 3] = ki; }
  }
  *(half8*)(qh + base)      = qlo_o;
  *(half8*)(qh + base + 64) = qhi_o;
  *(half8*)(kh + base)      = klo_o;
  *(half8*)(kh + base + 64) = khi_o;
  ((float4_*)(kout + base))[0]      = kr0;
  ((float4_*)(kout + base))[1]      = kr1;
  ((float4_*)(kout + base + 64))[0] = ki0;
  ((float4_*)(kout + base + 64))[1] = ki1;
}

// ---- V post: transposed fp16 v_t[B,H,D,S], fully vectorized (half8 both
// global sides; transpose through padded LDS).
__global__ __launch_bounds__(256) void vpost(const half_t* __restrict__ vh,
                                             half_t* __restrict__ vt) {
  __shared__ half_t t[64 * 72];
  int d0 = blockIdx.x * 64, s0 = blockIdx.y * 64, bh = blockIdx.z;
  int b = bh >> 4, h = bh & 15;
#pragma unroll
  for (int it = 0; it < 2; ++it) {          // load 64s x 64d, 8 d-elems/thread
    int e = it * 256 + threadIdx.x;         // 0..511
    int s = e >> 3, du = e & 7;
    half8 v = *(const half8*)(vh + (size_t)(b * SS + s0 + s) * HD + h * DH + d0 + du * 8);
#pragma unroll
    for (int j = 0; j < 8; ++j) t[(du * 8 + j) * 72 + s] = v[j];
  }
  __syncthreads();
#pragma unroll
  for (int it = 0; it < 2; ++it) {          // store 64d x 64s, 8 s-elems/thread
    int e = it * 256 + threadIdx.x;
    int d = e >> 3, su = e & 7;
    half8 v;
#pragma unroll
    for (int j = 0; j < 8; ++j) v[j] = t[d * 72 + su * 8 + j];
    *(half8*)(vt + ((size_t)bh * DH + d0 + d) * SS + s0 + su * 8) = v;
  }
}

// ============================================================================
// Flash attention, L2-direct (r5). K/V per head is 1 MB — L2-resident — so
// both MFMA B-operands are read straight from global in fragment layout
// (16B contiguous per lane). No K/V staging, no barriers, no vmcnt: waves are
// fully independent; latency hides via TLP (12 waves/CU target). Only the
// per-wave P tile round-trips through 9 KB of LDS.
// Grid: (32 q-tiles, B*NH), one q-tile per block, big tiles dispatched first.
// Constant-shift softmax: p = exp(s*scale - 2)  (exact: constant cancels).
// ============================================================================
#define SOFTMAX_SHIFT 2.0f

__global__ __launch_bounds__(256, 3) void attn_kernel(const half_t* __restrict__ qh,
                                                      const half_t* __restrict__ kh,
                                                      const half_t* __restrict__ vt,
                                                      half_t* __restrict__ oh) {
  __shared__ __align__(16) half_t lP[4 * 16 * 72];
  const int bh = blockIdx.y;
  const int b = bh >> 4, h = bh & 15;
  const int tid = threadIdx.x, wave = tid >> 6, lane = tid & 63;
  const int quad = lane >> 4, tl = lane & 15;
  const float scale = 0.08838834764831845f;  // 1/sqrt(128)

  half_t* myP = &lP[wave * 16 * 72];
  const half_t* qbase = qh + (size_t)(b * SS) * HD + h * DH;
  const half_t* khb   = kh + (size_t)(b * SS) * HD + h * DH;
  const half_t* vtb   = vt + (size_t)bh * DH * SS;

  const int qt = 31 - (int)blockIdx.x;       // largest tiles first
  const int q0 = qt * 64 + wave * 16;

  // Q fragments: A[m=tl][k=ks*32+quad*8+j]
  half8 qf[4];
#pragma unroll
  for (int ks = 0; ks < 4; ++ks)
    qf[ks] = *(const half8*)(qbase + (size_t)(q0 + tl) * HD + ks * 32 + quad * 8);

  float4_ oacc[8];
#pragma unroll
  for (int t = 0; t < 8; ++t)
#pragma unroll
    for (int r = 0; r < 4; ++r) oacc[t][r] = 0.f;
  float lpart[4] = {0.f, 0.f, 0.f, 0.f};

  for (int kt = 0; kt <= qt; ++kt) {
    // S = Q @ K^T  (16q x 64kv per wave), K fragments direct from L2
    float4_ sacc[4];
#pragma unroll
    for (int tn = 0; tn < 4; ++tn)
#pragma unroll
      for (int r = 0; r < 4; ++r) sacc[tn][r] = 0.f;
#pragma unroll
    for (int ks = 0; ks < 4; ++ks) {
#pragma unroll
      for (int tn = 0; tn < 4; ++tn) {
        half8 kf = *(const half8*)(khb + (size_t)(kt * 64 + tn * 16 + tl) * HD +
                                   ks * 32 + quad * 8);
        sacc[tn] = __builtin_amdgcn_mfma_f32_16x16x32_f16(qf[ks], kf, sacc[tn], 0, 0, 0);
      }
    }

    // p = exp(s*scale - C); causal mask only on diagonal tile
    if (kt == qt) {
#pragma unroll
      for (int tn = 0; tn < 4; ++tn) {
        int kvcol = kt * 64 + tn * 16 + tl;
#pragma unroll
        for (int j = 0; j < 4; ++j) {
          int qrow = q0 + quad * 4 + j;
          float sv = fmaf(sacc[tn][j], scale, -SOFTMAX_SHIFT);
          float pv = (kvcol > qrow) ? 0.f : __expf(sv);
          lpart[j] += pv;
          myP[(quad * 4 + j) * 72 + tn * 16 + tl] = (half_t)pv;
        }
      }
    } else {
#pragma unroll
      for (int tn = 0; tn < 4; ++tn)
#pragma unroll
        for (int j = 0; j < 4; ++j) {
          float pv = __expf(fmaf(sacc[tn][j], scale, -SOFTMAX_SHIFT));
          lpart[j] += pv;
          myP[(quad * 4 + j) * 72 + tn * 16 + tl] = (half_t)pv;
        }
    }

    // O += P @ V, V^T fragments direct from L2
#pragma unroll
    for (int ks2 = 0; ks2 < 2; ++ks2) {
      half8 pf = *(const half8*)&myP[tl * 72 + ks2 * 32 + quad * 8];
#pragma unroll
      for (int t = 0; t < 8; ++t) {
        half8 vf = *(const half8*)(vtb + (size_t)(t * 16 + tl) * SS + kt * 64 +
                                   ks2 * 32 + quad * 8);
        oacc[t] = __builtin_amdgcn_mfma_f32_16x16x32_f16(pf, vf, oacc[t], 0, 0, 0);
      }
    }
  }

  // final row-sum reduction across the 16 lanes of each quad
#pragma unroll
  for (int off = 1; off <= 8; off <<= 1)
#pragma unroll
    for (int j = 0; j < 4; ++j)
      lpart[j] += __shfl_xor(lpart[j], off, 64);
  float inv[4];
#pragma unroll
  for (int j = 0; j < 4; ++j) inv[j] = 1.f / lpart[j];
#pragma unroll
  for (int t = 0; t < 8; ++t)
#pragma unroll
    for (int j = 0; j < 4; ++j)
      oh[(size_t)(b * SS + q0 + quad * 4 + j) * HD + h * DH + t * 16 + tl] =
          (half_t)(oacc[t][j] * inv[j]);
}

extern "C" void kernel_launch(void* const* d_in, const int* in_sizes, int n_in,
                              void* d_out, int out_size, void* d_ws, size_t ws_size,
                              hipStream_t stream) {
  const float* x    = (const float*)d_in[0];
  const float* fr   = (const float*)d_in[1];
  const float* fi   = (const float*)d_in[2];
  // d_in[3] = attention_mask: exactly causal tril -> reproduced analytically
  const float* Wqkv = (const float*)d_in[4];
  const float* bqkv = (const float*)d_in[5];
  const float* Wo   = (const float*)d_in[6];

  float* out  = (float*)d_out;              // [2,2048,2048]
  float* kout = out + 8388608;              // [2,2048,16,128]
  float* vout = out + 16777216;             // [2,2048,16,128]

  char* ws = (char*)d_ws;
  half_t* xh  = (half_t*)(ws);                 // 16.8 MB
  half_t* wqh = (half_t*)(ws + 16777216);      // 25.2 MB
  half_t* woh = (half_t*)(ws + 41943040);      // 8.4 MB
  half_t* qh  = (half_t*)(ws + 50331648);      // 16.8 MB
  half_t* kh  = (half_t*)(ws + 67108864);      // 16.8 MB
  half_t* vh  = (half_t*)(ws + 83886080);      // 16.8 MB
  half_t* vt  = (half_t*)(ws + 100663296);     // 16.8 MB
  half_t* oh  = (half_t*)(ws + 117440512);     // 16.8 MB  (total 128 MB)

  conv_all<<<24576, 256, 0, stream>>>(x, Wqkv, Wo, xh, wqh, woh);
  gemm_qkv<<<dim3(48, 32), 256, 0, stream>>>(xh, wqh, bqkv, qh, kh, vh, vout);
  rope_post<<<2048, 256, 0, stream>>>(qh, kh, fr, fi, kout);
  vpost<<<dim3(2, 32, 32), 256, 0, stream>>>(vh, vt);
  attn_kernel<<<dim3(32, 32), 256, 0, stream>>>(qh, kh, vt, oh);
  gemm_out<<<dim3(16, 32), 256, 0, stream>>>(oh, woh, out);
}

// Round 6
// 437.654 us; speedup vs baseline: 1.8663x; 1.8663x over previous
//
#include <hip/hip_runtime.h>
#include <stdint.h>

// Problem constants (QwenAttention: B=2, S=2048, H=16, Dh=128, N_STATE=2048)
#define BS   2
#define SS   2048
#define NH   16
#define DH   128
#define HD   2048            // NH*DH == N_STATE
#define KDIM 2048
#define NT   32              // KDIM / 64 K-tiles

typedef _Float16 half_t;
typedef _Float16 half8 __attribute__((ext_vector_type(8)));
typedef _Float16 half4v __attribute__((ext_vector_type(4)));
typedef float   float4_ __attribute__((ext_vector_type(4)));

// ---- async global->LDS, 16B per lane (LDS dest must be wave-uniform base + lane*16)
__device__ __forceinline__ void async16(const void* g, void* l) {
  __builtin_amdgcn_global_load_lds(
      (__attribute__((address_space(1))) void*)(void*)g,
      (__attribute__((address_space(3))) void*)l,
      16, 0, 0);
}

// ---- fused fp32 -> fp16 conversion for x, Wqkv, Wo in ONE dispatch
#define XN4  2097152
#define WQ4  3145728
#define WO4  1048576
__global__ __launch_bounds__(256) void conv_all(const float* __restrict__ x,
                                                const float* __restrict__ Wqkv,
                                                const float* __restrict__ Wo,
                                                half_t* __restrict__ xh,
                                                half_t* __restrict__ wqh,
                                                half_t* __restrict__ woh) {
  int i = blockIdx.x * 256 + threadIdx.x;   // 0 .. 6291455
  const float* src; half_t* dst; int o;
  if (i < XN4)            { src = x;    dst = xh;  o = i; }
  else if (i < XN4 + WQ4) { src = Wqkv; dst = wqh; o = i - XN4; }
  else                    { src = Wo;   dst = woh; o = i - XN4 - WQ4; }
  float4 v = ((const float4*)src)[o];
  half4v hv;
  hv.x = (half_t)v.x; hv.y = (half_t)v.y; hv.z = (half_t)v.z; hv.w = (half_t)v.w;
  ((half4v*)dst)[o] = hv;
}

// ============================================================================
// GEMMs: 128x128 tile, BK=64, 4 waves (2x2). Distance-2 prefetch, double-
// buffered LDS, counted s_waitcnt vmcnt(8) (never drains to 0 in the main
// loop), raw s_barrier, setprio around MFMA. Verified: 880 TF (r3, 43% Mfma).
// LDS rows hold 8 chunks of 16B; chunk j of row r stored at j ^ (r&7) — XOR
// swizzle keeps ds_read_b128 bank-conflict-free (measured 0 conflicts).
// Staging swizzles the SOURCE address (global_load_lds dest must stay linear).
// ============================================================================

__device__ __forceinline__ const half8* lds_frag(const half_t* l, int row, int j) {
  return (const half8*)&l[(row * 8 + (j ^ (row & 7))) * 8];
}

// stage one 128x64 A-tile + 128x64 B-tile: 8 async16 per thread (256 threads)
__device__ __forceinline__ void stage8(const half_t* __restrict__ Ab,
                                       const half_t* __restrict__ Wb,
                                       half_t* dA, half_t* dB, int k0,
                                       int wave, int lane) {
#pragma unroll
  for (int i = 0; i < 4; ++i) {
    int p = (wave * 4 + i) * 64 + lane;       // chunk position 0..1023
    int r = p >> 3, j = (p & 7) ^ ((p >> 3) & 7);
    async16(Ab + (size_t)r * KDIM + k0 + j * 8, &dA[p * 8]);
    async16(Wb + (size_t)r * KDIM + k0 + j * 8, &dB[p * 8]);
  }
}

__device__ __forceinline__ void gemm_core(const half_t* __restrict__ Ab,
                                          const half_t* __restrict__ Wb,
                                          half_t* lA, half_t* lB,
                                          float4_ acc[4][4]) {
  const int tid = threadIdx.x, wave = tid >> 6, lane = tid & 63;
  const int quad = lane >> 4, tl = lane & 15;
  const int wm = wave >> 1, wn = wave & 1;

  stage8(Ab, Wb, lA, lB, 0, wave, lane);
  stage8(Ab, Wb, lA + 8192, lB + 8192, 64, wave, lane);

  for (int t = 0; t < NT; ++t) {
    if (t == NT - 1) asm volatile("s_waitcnt vmcnt(0)" ::: "memory");
    else             asm volatile("s_waitcnt vmcnt(8)" ::: "memory");
    __builtin_amdgcn_s_barrier();           // buf[t&1] fully staged, block-wide

    const half_t* cA = lA + (t & 1) * 8192;
    const half_t* cB = lB + (t & 1) * 8192;
    half8 af[4][2], bf[4][2];
#pragma unroll
    for (int ks = 0; ks < 2; ++ks) {
#pragma unroll
      for (int mi = 0; mi < 4; ++mi)
        af[mi][ks] = *lds_frag(cA, wm * 64 + mi * 16 + tl, ks * 4 + quad);
#pragma unroll
      for (int ni = 0; ni < 4; ++ni)
        bf[ni][ks] = *lds_frag(cB, wn * 64 + ni * 16 + tl, ks * 4 + quad);
    }
    asm volatile("s_waitcnt lgkmcnt(0)" ::: "memory");
    __builtin_amdgcn_sched_barrier(0);
    __builtin_amdgcn_s_barrier();           // all waves done reading buf[t&1]

    if (t + 2 < NT)                         // refill the buffer just freed
      stage8(Ab, Wb, lA + (t & 1) * 8192, lB + (t & 1) * 8192,
             (t + 2) * 64, wave, lane);
    __builtin_amdgcn_sched_barrier(0);      // keep stage issues ahead of MFMA

    __builtin_amdgcn_s_setprio(1);
#pragma unroll
    for (int mi = 0; mi < 4; ++mi)
#pragma unroll
      for (int ni = 0; ni < 4; ++ni)
#pragma unroll
        for (int ks = 0; ks < 2; ++ks)
          acc[mi][ni] = __builtin_amdgcn_mfma_f32_16x16x32_f16(
              af[mi][ks], bf[ni][ks], acc[mi][ni], 0, 0, 0);
    __builtin_amdgcn_s_setprio(0);
  }
}

// ---- GEMM1: qkv = x @ Wqkv^T + b; epilogue splits q/k/v fp16 and also emits
// v in fp32 straight from the accumulator (saves vpost a full fp32 write pass)
__global__ __launch_bounds__(256) void gemm_qkv(const half_t* __restrict__ A,
                                                const half_t* __restrict__ W,
                                                const float* __restrict__ bias,
                                                half_t* __restrict__ qh,
                                                half_t* __restrict__ kh,
                                                half_t* __restrict__ vh,
                                                float* __restrict__ vout) {
  __shared__ __align__(16) half_t lA[2 * 128 * 64];
  __shared__ __align__(16) half_t lB[2 * 128 * 64];
  const int tid = threadIdx.x, wave = tid >> 6, lane = tid & 63;
  const int quad = lane >> 4, tl = lane & 15;
  const int wm = wave >> 1, wn = wave & 1;
  const int bm = blockIdx.y * 128, bn = blockIdx.x * 128;

  float4_ acc[4][4];
#pragma unroll
  for (int mi = 0; mi < 4; ++mi)
#pragma unroll
    for (int ni = 0; ni < 4; ++ni)
#pragma unroll
      for (int r = 0; r < 4; ++r) acc[mi][ni][r] = 0.f;

  gemm_core(A + (size_t)bm * KDIM, W + (size_t)bn * KDIM, lA, lB, acc);

  // epilogue: C/D layout col=lane&15, row=quad*4+reg
#pragma unroll
  for (int mi = 0; mi < 4; ++mi) {
    int rowb = bm + wm * 64 + mi * 16 + quad * 4;
#pragma unroll
    for (int ni = 0; ni < 4; ++ni) {
      int col = bn + wn * 64 + ni * 16 + tl;
      float bv = bias[col];
#pragma unroll
      for (int r = 0; r < 4; ++r) {
        float v = acc[mi][ni][r] + bv;
        size_t off = (size_t)(rowb + r) * HD;
        if (col < 2048)       qh[off + col]        = (half_t)v;
        else if (col < 4096)  kh[off + col - 2048] = (half_t)v;
        else {
          vh[off + col - 4096]   = (half_t)v;
          vout[off + col - 4096] = v;
        }
      }
    }
  }
}

// ---- GEMM2: out = attn @ Wo^T (fp32 out, no bias)
__global__ __launch_bounds__(256) void gemm_out(const half_t* __restrict__ A,
                                                const half_t* __restrict__ W,
                                                float* __restrict__ out) {
  __shared__ __align__(16) half_t lA[2 * 128 * 64];
  __shared__ __align__(16) half_t lB[2 * 128 * 64];
  const int tid = threadIdx.x, wave = tid >> 6, lane = tid & 63;
  const int quad = lane >> 4, tl = lane & 15;
  const int wm = wave >> 1, wn = wave & 1;
  const int bm = blockIdx.y * 128, bn = blockIdx.x * 128;

  float4_ acc[4][4];
#pragma unroll
  for (int mi = 0; mi < 4; ++mi)
#pragma unroll
    for (int ni = 0; ni < 4; ++ni)
#pragma unroll
      for (int r = 0; r < 4; ++r) acc[mi][ni][r] = 0.f;

  gemm_core(A + (size_t)bm * KDIM, W + (size_t)bn * KDIM, lA, lB, acc);

#pragma unroll
  for (int mi = 0; mi < 4; ++mi) {
    int rowb = bm + wm * 64 + mi * 16 + quad * 4;
#pragma unroll
    for (int ni = 0; ni < 4; ++ni) {
      int col = bn + wn * 64 + ni * 16 + tl;
#pragma unroll
      for (int r = 0; r < 4; ++r)
        out[(size_t)(rowb + r) * HD + col] = acc[mi][ni][r];
    }
  }
}

// ---- Fused RoPE + V-transpose in one dispatch (disjoint data, grid halves).
// blocks [0,2048): RoPE on q,k (in-place, half8/float4 vectorized) + fp32 k out.
// blocks [2048,4096): v_t[B,H,D,S] transpose (half8 both sides, padded LDS).
__global__ __launch_bounds__(256) void rope_vpost(half_t* __restrict__ qh,
                                                  half_t* __restrict__ kh,
                                                  const float* __restrict__ fr,
                                                  const float* __restrict__ fi,
                                                  float* __restrict__ kout,
                                                  const half_t* __restrict__ vh,
                                                  half_t* __restrict__ vt) {
  __shared__ half_t t[64 * 72];
  if (blockIdx.x < 2048) {
    int n = blockIdx.x * 256 + threadIdx.x;   // B*S*NH*8 = 524288 threads
    int u = n & 7;
    int h = (n >> 3) & 15;
    int s = (n >> 7) & 2047;
    int b = n >> 18;
    size_t row = (size_t)(b * SS + s);
    size_t base = row * HD + h * DH + u * 8;
    const float4_* fr4 = (const float4_*)(fr + row * 64 + u * 8);
    const float4_* fi4 = (const float4_*)(fi + row * 64 + u * 8);
    float4_ frv0 = fr4[0], frv1 = fr4[1];
    float4_ fiv0 = fi4[0], fiv1 = fi4[1];
    half8 qlo = *(const half8*)(qh + base), qhi = *(const half8*)(qh + base + 64);
    half8 klo = *(const half8*)(kh + base), khi = *(const half8*)(kh + base + 64);
    half8 qlo_o, qhi_o, klo_o, khi_o;
    float4_ kr0, kr1, ki0, ki1;
#pragma unroll
    for (int j = 0; j < 8; ++j) {
      float cr = (j < 4) ? frv0[j & 3] : frv1[j & 3];
      float ci = (j < 4) ? fiv0[j & 3] : fiv1[j & 3];
      float xr = (float)qlo[j], xi = (float)qhi[j];
      qlo_o[j] = (half_t)(xr * cr - xi * ci);
      qhi_o[j] = (half_t)(xr * ci + xi * cr);
      xr = (float)klo[j]; xi = (float)khi[j];
      float kr = xr * cr - xi * ci, ki = xr * ci + xi * cr;
      klo_o[j] = (half_t)kr; khi_o[j] = (half_t)ki;
      if (j < 4) { kr0[j & 3] = kr; ki0[j & 3] = ki; }
      else       { kr1[j & 3] = kr; ki1[j & 3] = ki; }
    }
    *(half8*)(qh + base)      = qlo_o;
    *(half8*)(qh + base + 64) = qhi_o;
    *(half8*)(kh + base)      = klo_o;
    *(half8*)(kh + base + 64) = khi_o;
    ((float4_*)(kout + base))[0]      = kr0;
    ((float4_*)(kout + base))[1]      = kr1;
    ((float4_*)(kout + base + 64))[0] = ki0;
    ((float4_*)(kout + base + 64))[1] = ki1;
  } else {
    int bid = blockIdx.x - 2048;              // (2 d0) x (32 s0) x (32 bh)
    int d0 = (bid & 1) * 64, s0 = ((bid >> 1) & 31) * 64, bh = bid >> 6;
    int b = bh >> 4, h = bh & 15;
#pragma unroll
    for (int it = 0; it < 2; ++it) {          // load 64s x 64d, 8 d-elems/thread
      int e = it * 256 + threadIdx.x;         // 0..511
      int s = e >> 3, du = e & 7;
      half8 v = *(const half8*)(vh + (size_t)(b * SS + s0 + s) * HD + h * DH + d0 + du * 8);
#pragma unroll
      for (int j = 0; j < 8; ++j) t[(du * 8 + j) * 72 + s] = v[j];
    }
    __syncthreads();
#pragma unroll
    for (int it = 0; it < 2; ++it) {          // store 64d x 64s, 8 s-elems/thread
      int e = it * 256 + threadIdx.x;
      int d = e >> 3, su = e & 7;
      half8 v;
#pragma unroll
      for (int j = 0; j < 8; ++j) v[j] = t[d * 72 + su * 8 + j];
      *(half8*)(vt + ((size_t)bh * DH + d0 + d) * SS + s0 + su * 8) = v;
    }
  }
}

// ============================================================================
// Flash attention (r4 verified version). Grid (16 qtile-pairs, B*NH); block
// handles q-tiles {x, 31-x} -> uniform 33 KV-iterations per block.
// Constant-shift softmax: p = exp(s*scale - 2)  (exact: constant cancels).
// Double-buffered K/V staging, distance-1 prefetch, counted vmcnt(8) (never
// drains to 0 mid-loop), raw s_barrier, setprio(1) around both MFMA clusters.
// ============================================================================
#define SOFTMAX_SHIFT 2.0f

// stage K-tile [64][128] and V^T-tile [128][64], source-swizzled: 8 issues/thread
__device__ __forceinline__ void stage_kv(const half_t* __restrict__ khb,
                                         const half_t* __restrict__ vtb,
                                         half_t* dK, half_t* dV, int kt,
                                         int wave, int lane) {
#pragma unroll
  for (int i = 0; i < 4; ++i) {
    int p = (wave * 4 + i) * 64 + lane;       // chunk position 0..1023
    int rk = p >> 4, jk = (p & 15) ^ ((p >> 4) & 7);   // lK: 16 chunks/row
    async16(khb + (size_t)(kt * 64 + rk) * HD + jk * 8, &dK[p * 8]);
    int rv = p >> 3, jv = (p & 7) ^ ((p >> 3) & 7);    // lV: 8 chunks/row
    async16(vtb + (size_t)rv * SS + kt * 64 + jv * 8, &dV[p * 8]);
  }
}

__global__ __launch_bounds__(256) void attn_kernel(const half_t* __restrict__ qh,
                                                   const half_t* __restrict__ kh,
                                                   const half_t* __restrict__ vt,
                                                   half_t* __restrict__ oh) {
  __shared__ __align__(16) half_t lK[2 * 64 * 128];
  __shared__ __align__(16) half_t lV[2 * 128 * 64];
  __shared__ __align__(16) half_t lP[4 * 16 * 72];
  const int bh = blockIdx.y;
  const int b = bh >> 4, h = bh & 15;
  const int tid = threadIdx.x, wave = tid >> 6, lane = tid & 63;
  const int quad = lane >> 4, tl = lane & 15;
  const float scale = 0.08838834764831845f;  // 1/sqrt(128)

  half_t* myP = &lP[wave * 16 * 72];
  const half_t* qbase = qh + (size_t)(b * SS) * HD + h * DH;
  const half_t* khb   = kh + (size_t)(b * SS) * HD + h * DH;
  const half_t* vtb   = vt + (size_t)bh * DH * SS;

  for (int ph = 0; ph < 2; ++ph) {
    const int qt = ph ? (31 - (int)blockIdx.x) : (int)blockIdx.x;
    const int q0 = qt * 64 + wave * 16;

    // Q fragments: A[m=tl][k=ks*32+quad*8+j]
    half8 qf[4];
#pragma unroll
    for (int ks = 0; ks < 4; ++ks)
      qf[ks] = *(const half8*)(qbase + (size_t)(q0 + tl) * HD + ks * 32 + quad * 8);

    float4_ oacc[8];
#pragma unroll
    for (int t = 0; t < 8; ++t)
#pragma unroll
      for (int r = 0; r < 4; ++r) oacc[t][r] = 0.f;
    float lpart[4] = {0.f, 0.f, 0.f, 0.f};

    stage_kv(khb, vtb, lK, lV, 0, wave, lane);          // prologue: tile 0 -> buf0

    for (int kt = 0; kt <= qt; ++kt) {
      const half_t* cK = lK + (kt & 1) * 8192;
      const half_t* cV = lV + (kt & 1) * 8192;
      if (kt < qt) {                                    // prefetch next tile
        stage_kv(khb, vtb, lK + ((kt + 1) & 1) * 8192, lV + ((kt + 1) & 1) * 8192,
                 kt + 1, wave, lane);
        asm volatile("s_waitcnt vmcnt(8)" ::: "memory");  // tile kt landed
      } else {
        asm volatile("s_waitcnt vmcnt(0)" ::: "memory");
      }
      __builtin_amdgcn_s_barrier();                     // all waves' tile kt in LDS
      __builtin_amdgcn_sched_barrier(0);

      // S = Q @ K^T  (16q x 64kv per wave)
      float4_ sacc[4];
#pragma unroll
      for (int tn = 0; tn < 4; ++tn)
#pragma unroll
        for (int r = 0; r < 4; ++r) sacc[tn][r] = 0.f;
      __builtin_amdgcn_s_setprio(1);
#pragma unroll
      for (int ks = 0; ks < 4; ++ks) {
#pragma unroll
        for (int tn = 0; tn < 4; ++tn) {
          int row = tn * 16 + tl;
          int j = ks * 4 + quad;
          half8 kf = *(const half8*)&cK[(row * 16 + (j ^ (row & 7))) * 8];
          sacc[tn] = __builtin_amdgcn_mfma_f32_16x16x32_f16(qf[ks], kf, sacc[tn], 0, 0, 0);
        }
      }
      __builtin_amdgcn_s_setprio(0);

      // p = exp(s*scale - C); causal mask only on diagonal tile
      if (kt == qt) {
#pragma unroll
        for (int tn = 0; tn < 4; ++tn) {
          int kvcol = kt * 64 + tn * 16 + tl;
#pragma unroll
          for (int j = 0; j < 4; ++j) {
            int qrow = q0 + quad * 4 + j;
            float sv = fmaf(sacc[tn][j], scale, -SOFTMAX_SHIFT);
            float pv = (kvcol > qrow) ? 0.f : __expf(sv);
            lpart[j] += pv;
            myP[(quad * 4 + j) * 72 + tn * 16 + tl] = (half_t)pv;
          }
        }
      } else {
#pragma unroll
        for (int tn = 0; tn < 4; ++tn)
#pragma unroll
          for (int j = 0; j < 4; ++j) {
            float pv = __expf(fmaf(sacc[tn][j], scale, -SOFTMAX_SHIFT));
            lpart[j] += pv;
            myP[(quad * 4 + j) * 72 + tn * 16 + tl] = (half_t)pv;
          }
      }

      // O += P @ V
      __builtin_amdgcn_s_setprio(1);
#pragma unroll
      for (int ks2 = 0; ks2 < 2; ++ks2) {
        half8 pf = *(const half8*)&myP[tl * 72 + ks2 * 32 + quad * 8];
#pragma unroll
        for (int t = 0; t < 8; ++t) {
          int row = t * 16 + tl;
          int j = ks2 * 4 + quad;
          half8 vf = *(const half8*)&cV[(row * 8 + (j ^ (row & 7))) * 8];
          oacc[t] = __builtin_amdgcn_mfma_f32_16x16x32_f16(pf, vf, oacc[t], 0, 0, 0);
        }
      }
      __builtin_amdgcn_s_setprio(0);
      __builtin_amdgcn_s_barrier();          // buf[kt&1] free for next overwrite
    }

    // final row-sum reduction across the 16 lanes of each quad
#pragma unroll
    for (int off = 1; off <= 8; off <<= 1)
#pragma unroll
      for (int j = 0; j < 4; ++j)
        lpart[j] += __shfl_xor(lpart[j], off, 64);
    float inv[4];
#pragma unroll
    for (int j = 0; j < 4; ++j) inv[j] = 1.f / lpart[j];
#pragma unroll
    for (int t = 0; t < 8; ++t)
#pragma unroll
      for (int j = 0; j < 4; ++j)
        oh[(size_t)(b * SS + q0 + quad * 4 + j) * HD + h * DH + t * 16 + tl] =
            (half_t)(oacc[t][j] * inv[j]);
  }
}

extern "C" void kernel_launch(void* const* d_in, const int* in_sizes, int n_in,
                              void* d_out, int out_size, void* d_ws, size_t ws_size,
                              hipStream_t stream) {
  const float* x    = (const float*)d_in[0];
  const float* fr   = (const float*)d_in[1];
  const float* fi   = (const float*)d_in[2];
  // d_in[3] = attention_mask: exactly causal tril -> reproduced analytically
  const float* Wqkv = (const float*)d_in[4];
  const float* bqkv = (const float*)d_in[5];
  const float* Wo   = (const float*)d_in[6];

  float* out  = (float*)d_out;              // [2,2048,2048]
  float* kout = out + 8388608;              // [2,2048,16,128]
  float* vout = out + 16777216;             // [2,2048,16,128]

  char* ws = (char*)d_ws;
  half_t* xh  = (half_t*)(ws);                 // 16.8 MB
  half_t* wqh = (half_t*)(ws + 16777216);      // 25.2 MB
  half_t* woh = (half_t*)(ws + 41943040);      // 8.4 MB
  half_t* qh  = (half_t*)(ws + 50331648);      // 16.8 MB
  half_t* kh  = (half_t*)(ws + 67108864);      // 16.8 MB
  half_t* vh  = (half_t*)(ws + 83886080);      // 16.8 MB
  half_t* vt  = (half_t*)(ws + 100663296);     // 16.8 MB
  half_t* oh  = (half_t*)(ws + 117440512);     // 16.8 MB  (total 128 MB)

  conv_all<<<24576, 256, 0, stream>>>(x, Wqkv, Wo, xh, wqh, woh);
  gemm_qkv<<<dim3(48, 32), 256, 0, stream>>>(xh, wqh, bqkv, qh, kh, vh, vout);
  rope_vpost<<<4096, 256, 0, stream>>>(qh, kh, fr, fi, kout, vh, vt);
  attn_kernel<<<dim3(16, 32), 256, 0, stream>>>(qh, kh, vt, oh);
  gemm_out<<<dim3(16, 32), 256, 0, stream>>>(oh, woh, out);
}

// Round 7
// 427.017 us; speedup vs baseline: 1.9128x; 1.0249x over previous
//
#include <hip/hip_runtime.h>
#include <stdint.h>

// Problem constants (QwenAttention: B=2, S=2048, H=16, Dh=128, N_STATE=2048)
#define BS   2
#define SS   2048
#define NH   16
#define DH   128
#define HD   2048            // NH*DH == N_STATE
#define KDIM 2048
#define NT   32              // KDIM / 64 K-tiles

typedef _Float16 half_t;
typedef _Float16 half8 __attribute__((ext_vector_type(8)));
typedef _Float16 half4v __attribute__((ext_vector_type(4)));
typedef float   float4_ __attribute__((ext_vector_type(4)));

// ---- async global->LDS, 16B per lane (LDS dest must be wave-uniform base + lane*16)
__device__ __forceinline__ void async16(const void* g, void* l) {
  __builtin_amdgcn_global_load_lds(
      (__attribute__((address_space(1))) void*)(void*)g,
      (__attribute__((address_space(3))) void*)l,
      16, 0, 0);
}

// ---- fused fp32 -> fp16 conversion for x, Wqkv, Wo in ONE dispatch
#define XN4  2097152
#define WQ4  3145728
#define WO4  1048576
__global__ __launch_bounds__(256) void conv_all(const float* __restrict__ x,
                                                const float* __restrict__ Wqkv,
                                                const float* __restrict__ Wo,
                                                half_t* __restrict__ xh,
                                                half_t* __restrict__ wqh,
                                                half_t* __restrict__ woh) {
  int i = blockIdx.x * 256 + threadIdx.x;   // 0 .. 6291455
  const float* src; half_t* dst; int o;
  if (i < XN4)            { src = x;    dst = xh;  o = i; }
  else if (i < XN4 + WQ4) { src = Wqkv; dst = wqh; o = i - XN4; }
  else                    { src = Wo;   dst = woh; o = i - XN4 - WQ4; }
  float4 v = ((const float4*)src)[o];
  half4v hv;
  hv.x = (half_t)v.x; hv.y = (half_t)v.y; hv.z = (half_t)v.z; hv.w = (half_t)v.w;
  ((half4v*)dst)[o] = hv;
}

// ============================================================================
// GEMMs: 128x128 tile, BK=64, 4 waves (2x2). Distance-2 prefetch, double-
// buffered LDS, counted s_waitcnt vmcnt(8) (never drains to 0 in the main
// loop), raw s_barrier, setprio around MFMA. Verified: 880 TF (r3/r6, ~42%).
// LDS rows hold 8 chunks of 16B; chunk j of row r stored at j ^ (r&7) — XOR
// swizzle keeps ds_read_b128 bank-conflict-free (measured 0 conflicts).
// Staging swizzles the SOURCE address (global_load_lds dest must stay linear).
// ============================================================================

__device__ __forceinline__ const half8* lds_frag(const half_t* l, int row, int j) {
  return (const half8*)&l[(row * 8 + (j ^ (row & 7))) * 8];
}

// stage one 128x64 A-tile + 128x64 B-tile: 8 async16 per thread (256 threads)
__device__ __forceinline__ void stage8(const half_t* __restrict__ Ab,
                                       const half_t* __restrict__ Wb,
                                       half_t* dA, half_t* dB, int k0,
                                       int wave, int lane) {
#pragma unroll
  for (int i = 0; i < 4; ++i) {
    int p = (wave * 4 + i) * 64 + lane;       // chunk position 0..1023
    int r = p >> 3, j = (p & 7) ^ ((p >> 3) & 7);
    async16(Ab + (size_t)r * KDIM + k0 + j * 8, &dA[p * 8]);
    async16(Wb + (size_t)r * KDIM + k0 + j * 8, &dB[p * 8]);
  }
}

__device__ __forceinline__ void gemm_core(const half_t* __restrict__ Ab,
                                          const half_t* __restrict__ Wb,
                                          half_t* lA, half_t* lB,
                                          float4_ acc[4][4]) {
  const int tid = threadIdx.x, wave = tid >> 6, lane = tid & 63;
  const int quad = lane >> 4, tl = lane & 15;
  const int wm = wave >> 1, wn = wave & 1;

  stage8(Ab, Wb, lA, lB, 0, wave, lane);
  stage8(Ab, Wb, lA + 8192, lB + 8192, 64, wave, lane);

  for (int t = 0; t < NT; ++t) {
    if (t == NT - 1) asm volatile("s_waitcnt vmcnt(0)" ::: "memory");
    else             asm volatile("s_waitcnt vmcnt(8)" ::: "memory");
    __builtin_amdgcn_s_barrier();           // buf[t&1] fully staged, block-wide

    const half_t* cA = lA + (t & 1) * 8192;
    const half_t* cB = lB + (t & 1) * 8192;
    half8 af[4][2], bf[4][2];
#pragma unroll
    for (int ks = 0; ks < 2; ++ks) {
#pragma unroll
      for (int mi = 0; mi < 4; ++mi)
        af[mi][ks] = *lds_frag(cA, wm * 64 + mi * 16 + tl, ks * 4 + quad);
#pragma unroll
      for (int ni = 0; ni < 4; ++ni)
        bf[ni][ks] = *lds_frag(cB, wn * 64 + ni * 16 + tl, ks * 4 + quad);
    }
    asm volatile("s_waitcnt lgkmcnt(0)" ::: "memory");
    __builtin_amdgcn_sched_barrier(0);
    __builtin_amdgcn_s_barrier();           // all waves done reading buf[t&1]

    if (t + 2 < NT)                         // refill the buffer just freed
      stage8(Ab, Wb, lA + (t & 1) * 8192, lB + (t & 1) * 8192,
             (t + 2) * 64, wave, lane);
    __builtin_amdgcn_sched_barrier(0);      // keep stage issues ahead of MFMA

    __builtin_amdgcn_s_setprio(1);
#pragma unroll
    for (int mi = 0; mi < 4; ++mi)
#pragma unroll
      for (int ni = 0; ni < 4; ++ni)
#pragma unroll
        for (int ks = 0; ks < 2; ++ks)
          acc[mi][ni] = __builtin_amdgcn_mfma_f32_16x16x32_f16(
              af[mi][ks], bf[ni][ks], acc[mi][ni], 0, 0, 0);
    __builtin_amdgcn_s_setprio(0);
  }
}

// ---- GEMM1: qkv = x @ Wqkv^T + b; epilogue splits q/k/v fp16 and also emits
// v in fp32 straight from the accumulator (saves vpost a full fp32 write pass)
__global__ __launch_bounds__(256) void gemm_qkv(const half_t* __restrict__ A,
                                                const half_t* __restrict__ W,
                                                const float* __restrict__ bias,
                                                half_t* __restrict__ qh,
                                                half_t* __restrict__ kh,
                                                half_t* __restrict__ vh,
                                                float* __restrict__ vout) {
  __shared__ __align__(16) half_t lA[2 * 128 * 64];
  __shared__ __align__(16) half_t lB[2 * 128 * 64];
  const int tid = threadIdx.x, wave = tid >> 6, lane = tid & 63;
  const int quad = lane >> 4, tl = lane & 15;
  const int wm = wave >> 1, wn = wave & 1;
  const int bm = blockIdx.y * 128, bn = blockIdx.x * 128;

  float4_ acc[4][4];
#pragma unroll
  for (int mi = 0; mi < 4; ++mi)
#pragma unroll
    for (int ni = 0; ni < 4; ++ni)
#pragma unroll
      for (int r = 0; r < 4; ++r) acc[mi][ni][r] = 0.f;

  gemm_core(A + (size_t)bm * KDIM, W + (size_t)bn * KDIM, lA, lB, acc);

  // epilogue: C/D layout col=lane&15, row=quad*4+reg
#pragma unroll
  for (int mi = 0; mi < 4; ++mi) {
    int rowb = bm + wm * 64 + mi * 16 + quad * 4;
#pragma unroll
    for (int ni = 0; ni < 4; ++ni) {
      int col = bn + wn * 64 + ni * 16 + tl;
      float bv = bias[col];
#pragma unroll
      for (int r = 0; r < 4; ++r) {
        float v = acc[mi][ni][r] + bv;
        size_t off = (size_t)(rowb + r) * HD;
        if (col < 2048)       qh[off + col]        = (half_t)v;
        else if (col < 4096)  kh[off + col - 2048] = (half_t)v;
        else {
          vh[off + col - 4096]   = (half_t)v;
          vout[off + col - 4096] = v;
        }
      }
    }
  }
}

// ---- GEMM2: out = attn @ Wo^T (fp32 out, no bias)
__global__ __launch_bounds__(256) void gemm_out(const half_t* __restrict__ A,
                                                const half_t* __restrict__ W,
                                                float* __restrict__ out) {
  __shared__ __align__(16) half_t lA[2 * 128 * 64];
  __shared__ __align__(16) half_t lB[2 * 128 * 64];
  const int tid = threadIdx.x, wave = tid >> 6, lane = tid & 63;
  const int quad = lane >> 4, tl = lane & 15;
  const int wm = wave >> 1, wn = wave & 1;
  const int bm = blockIdx.y * 128, bn = blockIdx.x * 128;

  float4_ acc[4][4];
#pragma unroll
  for (int mi = 0; mi < 4; ++mi)
#pragma unroll
    for (int ni = 0; ni < 4; ++ni)
#pragma unroll
      for (int r = 0; r < 4; ++r) acc[mi][ni][r] = 0.f;

  gemm_core(A + (size_t)bm * KDIM, W + (size_t)bn * KDIM, lA, lB, acc);

#pragma unroll
  for (int mi = 0; mi < 4; ++mi) {
    int rowb = bm + wm * 64 + mi * 16 + quad * 4;
#pragma unroll
    for (int ni = 0; ni < 4; ++ni) {
      int col = bn + wn * 64 + ni * 16 + tl;
#pragma unroll
      for (int r = 0; r < 4; ++r)
        out[(size_t)(rowb + r) * HD + col] = acc[mi][ni][r];
    }
  }
}

// ---- Fused RoPE + V-transpose in one dispatch (disjoint data, grid halves).
// blocks [0,2048): RoPE on q,k (in-place, half8/float4 vectorized) + fp32 k out.
// blocks [2048,4096): v_t[B,H,D,S] transpose (half8 both sides, padded LDS).
__global__ __launch_bounds__(256) void rope_vpost(half_t* __restrict__ qh,
                                                  half_t* __restrict__ kh,
                                                  const float* __restrict__ fr,
                                                  const float* __restrict__ fi,
                                                  float* __restrict__ kout,
                                                  const half_t* __restrict__ vh,
                                                  half_t* __restrict__ vt) {
  __shared__ half_t t[64 * 72];
  if (blockIdx.x < 2048) {
    int n = blockIdx.x * 256 + threadIdx.x;   // B*S*NH*8 = 524288 threads
    int u = n & 7;
    int h = (n >> 3) & 15;
    int s = (n >> 7) & 2047;
    int b = n >> 18;
    size_t row = (size_t)(b * SS + s);
    size_t base = row * HD + h * DH + u * 8;
    const float4_* fr4 = (const float4_*)(fr + row * 64 + u * 8);
    const float4_* fi4 = (const float4_*)(fi + row * 64 + u * 8);
    float4_ frv0 = fr4[0], frv1 = fr4[1];
    float4_ fiv0 = fi4[0], fiv1 = fi4[1];
    half8 qlo = *(const half8*)(qh + base), qhi = *(const half8*)(qh + base + 64);
    half8 klo = *(const half8*)(kh + base), khi = *(const half8*)(kh + base + 64);
    half8 qlo_o, qhi_o, klo_o, khi_o;
    float4_ kr0, kr1, ki0, ki1;
#pragma unroll
    for (int j = 0; j < 8; ++j) {
      float cr = (j < 4) ? frv0[j & 3] : frv1[j & 3];
      float ci = (j < 4) ? fiv0[j & 3] : fiv1[j & 3];
      float xr = (float)qlo[j], xi = (float)qhi[j];
      qlo_o[j] = (half_t)(xr * cr - xi * ci);
      qhi_o[j] = (half_t)(xr * ci + xi * cr);
      xr = (float)klo[j]; xi = (float)khi[j];
      float kr = xr * cr - xi * ci, ki = xr * ci + xi * cr;
      klo_o[j] = (half_t)kr; khi_o[j] = (half_t)ki;
      if (j < 4) { kr0[j & 3] = kr; ki0[j & 3] = ki; }
      else       { kr1[j & 3] = kr; ki1[j & 3] = ki; }
    }
    *(half8*)(qh + base)      = qlo_o;
    *(half8*)(qh + base + 64) = qhi_o;
    *(half8*)(kh + base)      = klo_o;
    *(half8*)(kh + base + 64) = khi_o;
    ((float4_*)(kout + base))[0]      = kr0;
    ((float4_*)(kout + base))[1]      = kr1;
    ((float4_*)(kout + base + 64))[0] = ki0;
    ((float4_*)(kout + base + 64))[1] = ki1;
  } else {
    int bid = blockIdx.x - 2048;              // (2 d0) x (32 s0) x (32 bh)
    int d0 = (bid & 1) * 64, s0 = ((bid >> 1) & 31) * 64, bh = bid >> 6;
    int b = bh >> 4, h = bh & 15;
#pragma unroll
    for (int it = 0; it < 2; ++it) {          // load 64s x 64d, 8 d-elems/thread
      int e = it * 256 + threadIdx.x;         // 0..511
      int s = e >> 3, du = e & 7;
      half8 v = *(const half8*)(vh + (size_t)(b * SS + s0 + s) * HD + h * DH + d0 + du * 8);
#pragma unroll
      for (int j = 0; j < 8; ++j) t[(du * 8 + j) * 72 + s] = v[j];
    }
    __syncthreads();
#pragma unroll
    for (int it = 0; it < 2; ++it) {          // store 64d x 64s, 8 s-elems/thread
      int e = it * 256 + threadIdx.x;
      int d = e >> 3, su = e & 7;
      half8 v;
#pragma unroll
      for (int j = 0; j < 8; ++j) v[j] = t[d * 72 + su * 8 + j];
      *(half8*)(vt + ((size_t)bh * DH + d0 + d) * SS + s0 + su * 8) = v;
    }
  }
}

// ============================================================================
// Flash attention r7: 128-row q-tiles, 8 waves (512 thr), 1 block/CU.
// - Each wave keeps the verified 16-row fragment math; 8 waves share each
//   staged K/V tile -> staging bytes + barriers per MFMA halve vs r6.
// - XCD-aware block decode: bh = (b%8)*4 + (b/8)%4 clusters 4 heads (4 MB of
//   K+V^T) per XCD L2 -> staging re-reads become L2 hits.
// - Pairs {x,15-x} of 128-row q-tiles -> uniform 34 kv-iters; grid 256 = 1/CU.
// - Double-buffered staging, distance-1 prefetch, counted vmcnt(4) (never 0
//   mid-loop), raw s_barrier, setprio(1) around MFMA clusters.
// Constant-shift softmax: p = exp(s*scale - 2)  (exact: constant cancels).
// ============================================================================
#define SOFTMAX_SHIFT 2.0f

// stage K-tile [64][128] and V^T-tile [128][64], source-swizzled: 4 issues/thread
__device__ __forceinline__ void stage_kv(const half_t* __restrict__ khb,
                                         const half_t* __restrict__ vtb,
                                         half_t* dK, half_t* dV, int kt, int tid) {
#pragma unroll
  for (int i = 0; i < 2; ++i) {
    int p = i * 512 + tid;                    // chunk position 0..1023
    int rk = p >> 4, jk = (p & 15) ^ ((p >> 4) & 7);   // lK: 16 chunks/row
    async16(khb + (size_t)(kt * 64 + rk) * HD + jk * 8, &dK[p * 8]);
    int rv = p >> 3, jv = (p & 7) ^ ((p >> 3) & 7);    // lV: 8 chunks/row
    async16(vtb + (size_t)rv * SS + kt * 64 + jv * 8, &dV[p * 8]);
  }
}

__global__ __launch_bounds__(512) void attn_kernel(const half_t* __restrict__ qh,
                                                   const half_t* __restrict__ kh,
                                                   const half_t* __restrict__ vt,
                                                   half_t* __restrict__ oh) {
  __shared__ __align__(16) half_t lK[2 * 64 * 128];
  __shared__ __align__(16) half_t lV[2 * 128 * 64];
  __shared__ __align__(16) half_t lP[8 * 16 * 72];
  // XCD-aware decode: 8 XCDs x {4 heads x 8 q-pairs}; b%8 = XCD (heuristic)
  const int bid = blockIdx.x;
  const int bh = (bid & 7) * 4 + ((bid >> 3) & 3);
  const int qp = bid >> 5;                   // 0..7
  const int b = bh >> 4, h = bh & 15;
  const int tid = threadIdx.x, wave = tid >> 6, lane = tid & 63;
  const int quad = lane >> 4, tl = lane & 15;
  const float scale = 0.08838834764831845f;  // 1/sqrt(128)

  half_t* myP = &lP[wave * 16 * 72];
  const half_t* qbase = qh + (size_t)(b * SS) * HD + h * DH;
  const half_t* khb   = kh + (size_t)(b * SS) * HD + h * DH;
  const half_t* vtb   = vt + (size_t)bh * DH * SS;

  for (int ph = 0; ph < 2; ++ph) {
    const int qt = ph ? (15 - qp) : qp;       // 128-row q-tile index
    const int q0 = qt * 128 + wave * 16;
    const int nkt = 2 * qt + 2;               // kv-tiles covering rows < (qt+1)*128

    // Q fragments: A[m=tl][k=ks*32+quad*8+j]
    half8 qf[4];
#pragma unroll
    for (int ks = 0; ks < 4; ++ks)
      qf[ks] = *(const half8*)(qbase + (size_t)(q0 + tl) * HD + ks * 32 + quad * 8);

    float4_ oacc[8];
#pragma unroll
    for (int t = 0; t < 8; ++t)
#pragma unroll
      for (int r = 0; r < 4; ++r) oacc[t][r] = 0.f;
    float lpart[4] = {0.f, 0.f, 0.f, 0.f};

    stage_kv(khb, vtb, lK, lV, 0, tid);       // prologue: tile 0 -> buf0

    for (int kt = 0; kt < nkt; ++kt) {
      const half_t* cK = lK + (kt & 1) * 8192;
      const half_t* cV = lV + (kt & 1) * 8192;
      if (kt + 1 < nkt) {                     // prefetch next tile
        stage_kv(khb, vtb, lK + ((kt + 1) & 1) * 8192, lV + ((kt + 1) & 1) * 8192,
                 kt + 1, tid);
        asm volatile("s_waitcnt vmcnt(4)" ::: "memory");  // tile kt landed
      } else {
        asm volatile("s_waitcnt vmcnt(0)" ::: "memory");
      }
      __builtin_amdgcn_s_barrier();           // all waves' tile kt in LDS
      __builtin_amdgcn_sched_barrier(0);

      // S = Q @ K^T  (16q x 64kv per wave)
      float4_ sacc[4];
#pragma unroll
      for (int tn = 0; tn < 4; ++tn)
#pragma unroll
        for (int r = 0; r < 4; ++r) sacc[tn][r] = 0.f;
      __builtin_amdgcn_s_setprio(1);
#pragma unroll
      for (int ks = 0; ks < 4; ++ks) {
#pragma unroll
        for (int tn = 0; tn < 4; ++tn) {
          int row = tn * 16 + tl;
          int j = ks * 4 + quad;
          half8 kf = *(const half8*)&cK[(row * 16 + (j ^ (row & 7))) * 8];
          sacc[tn] = __builtin_amdgcn_mfma_f32_16x16x32_f16(qf[ks], kf, sacc[tn], 0, 0, 0);
        }
      }
      __builtin_amdgcn_s_setprio(0);

      // p = exp(s*scale - C); causal mask in the diagonal region (wave-uniform)
      if (kt * 64 + 63 > q0) {
#pragma unroll
        for (int tn = 0; tn < 4; ++tn) {
          int kvcol = kt * 64 + tn * 16 + tl;
#pragma unroll
          for (int j = 0; j < 4; ++j) {
            int qrow = q0 + quad * 4 + j;
            float sv = fmaf(sacc[tn][j], scale, -SOFTMAX_SHIFT);
            float pv = (kvcol > qrow) ? 0.f : __expf(sv);
            lpart[j] += pv;
            myP[(quad * 4 + j) * 72 + tn * 16 + tl] = (half_t)pv;
          }
        }
      } else {
#pragma unroll
        for (int tn = 0; tn < 4; ++tn)
#pragma unroll
          for (int j = 0; j < 4; ++j) {
            float pv = __expf(fmaf(sacc[tn][j], scale, -SOFTMAX_SHIFT));
            lpart[j] += pv;
            myP[(quad * 4 + j) * 72 + tn * 16 + tl] = (half_t)pv;
          }
      }

      // O += P @ V
      __builtin_amdgcn_s_setprio(1);
#pragma unroll
      for (int ks2 = 0; ks2 < 2; ++ks2) {
        half8 pf = *(const half8*)&myP[tl * 72 + ks2 * 32 + quad * 8];
#pragma unroll
        for (int t = 0; t < 8; ++t) {
          int row = t * 16 + tl;
          int j = ks2 * 4 + quad;
          half8 vf = *(const half8*)&cV[(row * 8 + (j ^ (row & 7))) * 8];
          oacc[t] = __builtin_amdgcn_mfma_f32_16x16x32_f16(pf, vf, oacc[t], 0, 0, 0);
        }
      }
      __builtin_amdgcn_s_setprio(0);
      __builtin_amdgcn_s_barrier();          // buf[kt&1] free for next overwrite
    }

    // final row-sum reduction across the 16 lanes of each quad
#pragma unroll
    for (int off = 1; off <= 8; off <<= 1)
#pragma unroll
      for (int j = 0; j < 4; ++j)
        lpart[j] += __shfl_xor(lpart[j], off, 64);
    float inv[4];
#pragma unroll
    for (int j = 0; j < 4; ++j) inv[j] = 1.f / lpart[j];
#pragma unroll
    for (int t = 0; t < 8; ++t)
#pragma unroll
      for (int j = 0; j < 4; ++j)
        oh[(size_t)(b * SS + q0 + quad * 4 + j) * HD + h * DH + t * 16 + tl] =
            (half_t)(oacc[t][j] * inv[j]);
  }
}

extern "C" void kernel_launch(void* const* d_in, const int* in_sizes, int n_in,
                              void* d_out, int out_size, void* d_ws, size_t ws_size,
                              hipStream_t stream) {
  const float* x    = (const float*)d_in[0];
  const float* fr   = (const float*)d_in[1];
  const float* fi   = (const float*)d_in[2];
  // d_in[3] = attention_mask: exactly causal tril -> reproduced analytically
  const float* Wqkv = (const float*)d_in[4];
  const float* bqkv = (const float*)d_in[5];
  const float* Wo   = (const float*)d_in[6];

  float* out  = (float*)d_out;              // [2,2048,2048]
  float* kout = out + 8388608;              // [2,2048,16,128]
  float* vout = out + 16777216;             // [2,2048,16,128]

  char* ws = (char*)d_ws;
  half_t* xh  = (half_t*)(ws);                 // 16.8 MB
  half_t* wqh = (half_t*)(ws + 16777216);      // 25.2 MB
  half_t* woh = (half_t*)(ws + 41943040);      // 8.4 MB
  half_t* qh  = (half_t*)(ws + 50331648);      // 16.8 MB
  half_t* kh  = (half_t*)(ws + 67108864);      // 16.8 MB
  half_t* vh  = (half_t*)(ws + 83886080);      // 16.8 MB
  half_t* vt  = (half_t*)(ws + 100663296);     // 16.8 MB
  half_t* oh  = (half_t*)(ws + 117440512);     // 16.8 MB  (total 128 MB)

  conv_all<<<24576, 256, 0, stream>>>(x, Wqkv, Wo, xh, wqh, woh);
  gemm_qkv<<<dim3(48, 32), 256, 0, stream>>>(xh, wqh, bqkv, qh, kh, vh, vout);
  rope_vpost<<<4096, 256, 0, stream>>>(qh, kh, fr, fi, kout, vh, vt);
  attn_kernel<<<256, 512, 0, stream>>>(qh, kh, vt, oh);
  gemm_out<<<dim3(16, 32), 256, 0, stream>>>(oh, woh, out);
}